// Round 3
// baseline (1192.771 us; speedup 1.0000x reference)
//
#include <hip/hip_runtime.h>
#include <hip/hip_bf16.h>
#include <math.h>

typedef __hip_bfloat16 bf16;

#define B_ 64
#define C_ 512
#define N_ 1024
#define D_ 128
#define K_ 8

__device__ __forceinline__ float sigmoidf_(float x) { return 1.0f / (1.0f + expf(-x)); }
__device__ __forceinline__ float gelu_exact(float x) {
    return 0.5f * x * (1.0f + erff(x * 0.7071067811865476f));
}

// ---------------------------------------------------------------------------
// K1: inputs[b,n,:] = LN(x_flat @ Wp + bp) * g_in + b_in
// x is [B][C][N] (N=H*W); x_flat[b,n,c] = x[b,c,n].
// Block: 256 threads, tile = 64 rows (n) x 128 cols (d), k-tiles of 64 over C.
// ---------------------------------------------------------------------------
__global__ __launch_bounds__(256) void proj_ln_kernel(
    const float* __restrict__ x, const float* __restrict__ Wp,
    const float* __restrict__ bp, const float* __restrict__ g_in,
    const float* __restrict__ b_in, float* __restrict__ out)
{
    union SM {
        struct { float xs[64][67]; float ws[64][128]; } a;
        struct { float ps[64][129]; float m[64]; float r[64]; } b;
    };
    __shared__ SM sm;
    const int t = threadIdx.x;
    const int blk = blockIdx.x;
    const int b = blk >> 4;
    const int n0 = (blk & 15) << 6;
    const int nn2 = t & 31;      // row pair index (rows 2*nn2, 2*nn2+1)
    const int d0 = (t >> 5) << 4; // 16-wide d slice

    float acc0[16], acc1[16];
#pragma unroll
    for (int j = 0; j < 16; ++j) { acc0[j] = 0.0f; acc1[j] = 0.0f; }

    const float* xb = x + (size_t)b * (C_ * N_);
    for (int c0 = 0; c0 < C_; c0 += 64) {
#pragma unroll
        for (int i = 0; i < 16; ++i) {
            int idx = t + (i << 8);
            int cc = idx >> 6, n2 = idx & 63;
            sm.a.xs[cc][n2] = xb[(size_t)(c0 + cc) * N_ + n0 + n2];
        }
#pragma unroll
        for (int i = 0; i < 32; ++i) {
            int idx = t + (i << 8);
            int cc = idx >> 7, d = idx & 127;
            sm.a.ws[cc][d] = Wp[(size_t)(c0 + cc) * D_ + d];
        }
        __syncthreads();
        for (int cc = 0; cc < 64; ++cc) {
            float xv0 = sm.a.xs[cc][2 * nn2];
            float xv1 = sm.a.xs[cc][2 * nn2 + 1];
            const float* wr = &sm.a.ws[cc][d0];
#pragma unroll
            for (int j = 0; j < 16; ++j) {
                float w = wr[j];
                acc0[j] += xv0 * w;
                acc1[j] += xv1 * w;
            }
        }
        __syncthreads();
    }
    // add bp, stash rows for LN reduce
#pragma unroll
    for (int j = 0; j < 16; ++j) {
        float bpv = bp[d0 + j];
        acc0[j] += bpv; acc1[j] += bpv;
        sm.b.ps[2 * nn2][d0 + j] = acc0[j];
        sm.b.ps[2 * nn2 + 1][d0 + j] = acc1[j];
    }
    __syncthreads();
    // LN stats: wave w handles rows w*16..w*16+15
    {
        int wv = t >> 6, ln = t & 63;
        for (int i = 0; i < 16; ++i) {
            int row = wv * 16 + i;
            float v0 = sm.b.ps[row][ln];
            float v1 = sm.b.ps[row][ln + 64];
            float s = v0 + v1, s2 = v0 * v0 + v1 * v1;
            for (int o = 32; o > 0; o >>= 1) {
                s += __shfl_down(s, o, 64);
                s2 += __shfl_down(s2, o, 64);
            }
            if (ln == 0) {
                float m = s * (1.0f / 128.0f);
                float var = s2 * (1.0f / 128.0f) - m * m;
                sm.b.m[row] = m;
                sm.b.r[row] = rsqrtf(var + 1e-5f);
            }
        }
    }
    __syncthreads();
    {
        size_t base = (size_t)b * N_ + n0;
        int row = 2 * nn2;
        float m = sm.b.m[row], rr = sm.b.r[row];
        float* orow = out + (base + row) * D_ + d0;
#pragma unroll
        for (int j = 0; j < 16; ++j)
            orow[j] = (acc0[j] - m) * rr * g_in[d0 + j] + b_in[d0 + j];
        row = 2 * nn2 + 1;
        m = sm.b.m[row]; rr = sm.b.r[row];
        orow = out + (base + row) * D_ + d0;
#pragma unroll
        for (int j = 0; j < 16; ++j)
            orow[j] = (acc1[j] - m) * rr * g_in[d0 + j] + b_in[d0 + j];
    }
}

// ---------------------------------------------------------------------------
// K2: k = inputs@Wk + bk  (grid.y=0) ;  v = inputs@Wv + bv  (grid.y=1)
// ---------------------------------------------------------------------------
__global__ __launch_bounds__(256) void kv_kernel(
    const float* __restrict__ A,
    const float* __restrict__ Wk, const float* __restrict__ bk,
    const float* __restrict__ Wv, const float* __restrict__ bv,
    float* __restrict__ kout, float* __restrict__ vout)
{
    __shared__ float as[64][67];
    __shared__ float ws[64][128];
    const int t = threadIdx.x;
    const int row0 = blockIdx.x << 6;
    const float* Wm = blockIdx.y ? Wv : Wk;
    const float* bias = blockIdx.y ? bv : bk;
    float* outp = blockIdx.y ? vout : kout;
    const int rr2 = t & 31;
    const int d0 = (t >> 5) << 4;

    float acc0[16], acc1[16];
#pragma unroll
    for (int j = 0; j < 16; ++j) { acc0[j] = 0.0f; acc1[j] = 0.0f; }

    for (int c0 = 0; c0 < D_; c0 += 64) {
#pragma unroll
        for (int i = 0; i < 16; ++i) {
            int idx = t + (i << 8);
            int rr = idx >> 6, cc = idx & 63;
            as[cc][rr] = A[(size_t)(row0 + rr) * D_ + c0 + cc];
        }
#pragma unroll
        for (int i = 0; i < 32; ++i) {
            int idx = t + (i << 8);
            int cc = idx >> 7, d = idx & 127;
            ws[cc][d] = Wm[(c0 + cc) * D_ + d];
        }
        __syncthreads();
        for (int cc = 0; cc < 64; ++cc) {
            float a0 = as[cc][2 * rr2];
            float a1 = as[cc][2 * rr2 + 1];
            const float* wr = &ws[cc][d0];
#pragma unroll
            for (int j = 0; j < 16; ++j) {
                float w = wr[j];
                acc0[j] += a0 * w;
                acc1[j] += a1 * w;
            }
        }
        __syncthreads();
    }
    {
        int row = row0 + 2 * rr2;
        float* orow = outp + (size_t)row * D_ + d0;
#pragma unroll
        for (int j = 0; j < 16; ++j) orow[j] = acc0[j] + bias[d0 + j];
        orow += D_;
#pragma unroll
        for (int j = 0; j < 16; ++j) orow[j] = acc1[j] + bias[d0 + j];
    }
}

// ---------------------------------------------------------------------------
// K3: slots = slot_mu + exp(slot_log_sigma) * noise   (fp32 to ws)
// ---------------------------------------------------------------------------
__global__ __launch_bounds__(256) void slots_init_kernel(
    const float* __restrict__ noise, const float* __restrict__ mu,
    const float* __restrict__ lsig, float* __restrict__ slots)
{
    int idx = blockIdx.x * 256 + threadIdx.x;   // < 65536
    int kd = idx & (K_ * D_ - 1);
    slots[idx] = mu[kd] + expf(lsig[kd]) * noise[idx];
}

// ---------------------------------------------------------------------------
// K4: q = LN(slots)*g_slots+b_slots @ Wq + bq   (one block per b)
// ---------------------------------------------------------------------------
__global__ __launch_bounds__(256) void q_kernel(
    const float* __restrict__ slots,
    const float* __restrict__ g_slots, const float* __restrict__ b_slots,
    const float* __restrict__ Wq, const float* __restrict__ bq,
    float* __restrict__ qbuf)
{
    __shared__ float sl[8][128];
    __shared__ float sl2[8][128];
    __shared__ float mr[8], rs[8];
    const int t = threadIdx.x;
    const int b = blockIdx.x;
#pragma unroll
    for (int i = 0; i < 4; ++i) {
        int idx = t + (i << 8);
        int k = idx >> 7, d = idx & 127;
        sl[k][d] = slots[((size_t)b * K_ + k) * D_ + d];
    }
    __syncthreads();
    {
        int wv = t >> 6, ln = t & 63;
        for (int rep = 0; rep < 2; ++rep) {
            int row = wv + rep * 4;
            float v0 = sl[row][ln], v1 = sl[row][ln + 64];
            float s = v0 + v1, s2 = v0 * v0 + v1 * v1;
            for (int o = 32; o > 0; o >>= 1) {
                s += __shfl_down(s, o, 64);
                s2 += __shfl_down(s2, o, 64);
            }
            if (ln == 0) {
                float m = s * (1.0f / 128.0f);
                float var = s2 * (1.0f / 128.0f) - m * m;
                mr[row] = m; rs[row] = rsqrtf(var + 1e-5f);
            }
        }
    }
    __syncthreads();
#pragma unroll
    for (int i = 0; i < 4; ++i) {
        int idx = t + (i << 8);
        int k = idx >> 7, d = idx & 127;
        sl2[k][d] = (sl[k][d] - mr[k]) * rs[k] * g_slots[d] + b_slots[d];
    }
    __syncthreads();
    {
        int d = t & 127, kk = t >> 7;  // k = kk, kk+2, kk+4, kk+6
        float bqv = bq[d];
        float a0 = bqv, a1 = bqv, a2 = bqv, a3 = bqv;
        for (int c = 0; c < 128; ++c) {
            float w = Wq[c * D_ + d];
            a0 += sl2[kk][c] * w;
            a1 += sl2[kk + 2][c] * w;
            a2 += sl2[kk + 4][c] * w;
            a3 += sl2[kk + 6][c] * w;
        }
        size_t base = (size_t)b * K_ * D_ + d;
        qbuf[base + (kk)*D_] = a0;
        qbuf[base + (kk + 2) * D_] = a1;
        qbuf[base + (kk + 4) * D_] = a2;
        qbuf[base + (kk + 6) * D_] = a3;
    }
}

// ---------------------------------------------------------------------------
// K5a: logits -> softmax over K (axis=1) -> attn (fp32 ws; optionally fp32 out)
// grid: (N/64, B)
// ---------------------------------------------------------------------------
__global__ __launch_bounds__(256) void attn_kernel(
    const float* __restrict__ kbuf, const float* __restrict__ qbuf,
    float* __restrict__ attn, float* __restrict__ attn_out, int write_attn)
{
    __shared__ float qs[8][128];
    __shared__ float kt[64][129];
    __shared__ float lg[8][66];
    const int t = threadIdx.x;
    const int n0 = blockIdx.x << 6;
    const int b = blockIdx.y;
    const float SCALE = 0.08838834764831845f;

#pragma unroll
    for (int i = 0; i < 4; ++i) {
        int idx = t + (i << 8);
        int k = idx >> 7, d = idx & 127;
        qs[k][d] = qbuf[((size_t)b * K_ + k) * D_ + d];
    }
#pragma unroll
    for (int i = 0; i < 32; ++i) {
        int idx = t + (i << 8);
        int rr = idx >> 7, d = idx & 127;
        kt[rr][d] = kbuf[((size_t)b * N_ + n0 + rr) * D_ + d];
    }
    __syncthreads();
    {
        int nn = t & 63, kg = t >> 6;   // k = kg, kg+4
        float a0 = 0.0f, a1 = 0.0f;
        for (int d = 0; d < 128; ++d) {
            float kv = kt[nn][d];
            a0 += qs[kg][d] * kv;
            a1 += qs[kg + 4][d] * kv;
        }
        lg[kg][nn] = a0 * SCALE;
        lg[kg + 4][nn] = a1 * SCALE;
    }
    __syncthreads();
    if (t < 64) {
        int nn = t;
        float m = lg[0][nn];
#pragma unroll
        for (int k = 1; k < 8; ++k) m = fmaxf(m, lg[k][nn]);
        float s = 0.0f;
        float e[8];
#pragma unroll
        for (int k = 0; k < 8; ++k) { e[k] = expf(lg[k][nn] - m); s += e[k]; }
        float inv = 1.0f / s;
#pragma unroll
        for (int k = 0; k < 8; ++k) lg[k][nn] = e[k] * inv;
    }
    __syncthreads();
    {
        int nn = t & 63, kg = t >> 6;
        float p0 = lg[kg][nn], p1 = lg[kg + 4][nn];
        size_t i0 = ((size_t)b * K_ + kg) * N_ + n0 + nn;
        size_t i1 = ((size_t)b * K_ + kg + 4) * N_ + n0 + nn;
        attn[i0] = p0;
        attn[i1] = p1;
        if (write_attn) {
            attn_out[i0] = p0;
            attn_out[i1] = p1;
        }
    }
}

// ---------------------------------------------------------------------------
// K5b: updates[b,k,:] = (attn[b,k,:]/(sum_n attn + EPS)) @ v[b]   (block per b)
// ---------------------------------------------------------------------------
__global__ __launch_bounds__(256) void updates_kernel(
    const float* __restrict__ attn, const float* __restrict__ vbuf,
    float* __restrict__ upd)
{
    __shared__ float vt[64][129];
    __shared__ float at[8][66];
    __shared__ float red[8][33];
    __shared__ float Sinv[8];
    const int t = threadIdx.x;
    const int b = blockIdx.x;
    {
        int k = t >> 5, l = t & 31;
        const float* ar = attn + ((size_t)b * K_ + k) * N_;
        float p = 0.0f;
        for (int j = 0; j < 32; ++j) p += ar[l + 32 * j];
        red[k][l] = p;
    }
    __syncthreads();
    if (t < 8) {
        float s = 0.0f;
        for (int j = 0; j < 32; ++j) s += red[t][j];
        Sinv[t] = 1.0f / (s + 1e-8f);
    }
    __syncthreads();

    const int d = t & 127, kk = t >> 7;  // k = kk, kk+2, kk+4, kk+6
    float a0 = 0.0f, a1 = 0.0f, a2 = 0.0f, a3 = 0.0f;
    for (int nt = 0; nt < 16; ++nt) {
        int n0 = nt << 6;
#pragma unroll
        for (int i = 0; i < 32; ++i) {
            int idx = t + (i << 8);
            int rr = idx >> 7, dd = idx & 127;
            vt[rr][dd] = vbuf[((size_t)b * N_ + n0 + rr) * D_ + dd];
        }
#pragma unroll
        for (int i = 0; i < 2; ++i) {
            int idx = t + (i << 8);
            int k = idx >> 6, nn = idx & 63;
            at[k][nn] = attn[((size_t)b * K_ + k) * N_ + n0 + nn];
        }
        __syncthreads();
        for (int nn = 0; nn < 64; ++nn) {
            float vv = vt[nn][d];
            a0 += at[kk][nn] * vv;
            a1 += at[kk + 2][nn] * vv;
            a2 += at[kk + 4][nn] * vv;
            a3 += at[kk + 6][nn] * vv;
        }
        __syncthreads();
    }
    size_t base = (size_t)b * K_ * D_ + d;
    upd[base + (kk)*D_] = a0 * Sinv[kk];
    upd[base + (kk + 2) * D_] = a1 * Sinv[kk + 2];
    upd[base + (kk + 4) * D_] = a2 * Sinv[kk + 4];
    upd[base + (kk + 6) * D_] = a3 * Sinv[kk + 6];
}

// ---------------------------------------------------------------------------
// K6: fused GRUCell + LN + MLP(GELU) + residual.  Block per b (8 slots).
// ---------------------------------------------------------------------------
__global__ __launch_bounds__(256) void gru_mlp_kernel(
    const float* __restrict__ upd, float* __restrict__ slots,
    const float* __restrict__ W_ih, const float* __restrict__ W_hh,
    const float* __restrict__ b_ih, const float* __restrict__ b_hh,
    const float* __restrict__ W1, const float* __restrict__ b1,
    const float* __restrict__ W2, const float* __restrict__ b2,
    const float* __restrict__ g_mlp, const float* __restrict__ b_mlp,
    float* __restrict__ out_slots, int final_iter)
{
    __shared__ float Us[8][128], Hs[8][128];
    __shared__ float GX[8][384], GH[8][384];
    __shared__ float wbuf[8448];
    __shared__ float SN[8][128], T[8][128], HM[8][256];
    __shared__ float mr[8], rs[8];
    const int t = threadIdx.x;
    const int b = blockIdx.x;

#pragma unroll
    for (int i = 0; i < 4; ++i) {
        int idx = t + (i << 8);
        int k = idx >> 7, d = idx & 127;
        Us[k][d] = upd[((size_t)b * K_ + k) * D_ + d];
        Hs[k][d] = slots[((size_t)b * K_ + k) * D_ + d];
    }
    __syncthreads();
    // phase 1: GX = u @ W_ih^T + b_ih ; GH = h @ W_hh^T + b_hh
    for (int p = 0; p < 2; ++p) {
        const float* Wm = p ? W_hh : W_ih;
        const float* bias = p ? b_hh : b_ih;
        float (*src)[128] = p ? Hs : Us;
        float (*dst)[384] = p ? GH : GX;
        for (int jt = 0; jt < 6; ++jt) {
            int j0 = jt << 6;
#pragma unroll
            for (int i = 0; i < 32; ++i) {
                int idx = t + (i << 8);
                int jj = idx >> 7, d = idx & 127;
                wbuf[jj * 129 + d] = Wm[(j0 + jj) * D_ + d];
            }
            __syncthreads();
            {
                int jj = t & 63, rg = t >> 6;  // rows rg, rg+4
                float a0 = 0.0f, a1 = 0.0f;
                for (int d = 0; d < 128; ++d) {
                    float w = wbuf[jj * 129 + d];
                    a0 += src[rg][d] * w;
                    a1 += src[rg + 4][d] * w;
                }
                float bb = bias[j0 + jj];
                dst[rg][j0 + jj] = a0 + bb;
                dst[rg + 4][j0 + jj] = a1 + bb;
            }
            __syncthreads();
        }
    }
    // phase 2: gates + new slots (pre-MLP)
#pragma unroll
    for (int i = 0; i < 4; ++i) {
        int idx = t + (i << 8);
        int k = idx >> 7, j = idx & 127;
        float r = sigmoidf_(GX[k][j] + GH[k][j]);
        float z = sigmoidf_(GX[k][j + 128] + GH[k][j + 128]);
        float n = tanhf(GX[k][j + 256] + r * GH[k][j + 256]);
        SN[k][j] = (1.0f - z) * n + z * Hs[k][j];
    }
    __syncthreads();
    // LN over each of 8 rows
    {
        int wv = t >> 6, ln = t & 63;
        for (int rep = 0; rep < 2; ++rep) {
            int row = wv + rep * 4;
            float v0 = SN[row][ln], v1 = SN[row][ln + 64];
            float s = v0 + v1, s2 = v0 * v0 + v1 * v1;
            for (int o = 32; o > 0; o >>= 1) {
                s += __shfl_down(s, o, 64);
                s2 += __shfl_down(s2, o, 64);
            }
            if (ln == 0) {
                float m = s * (1.0f / 128.0f);
                float var = s2 * (1.0f / 128.0f) - m * m;
                mr[row] = m; rs[row] = rsqrtf(var + 1e-5f);
            }
        }
    }
    __syncthreads();
#pragma unroll
    for (int i = 0; i < 4; ++i) {
        int idx = t + (i << 8);
        int k = idx >> 7, j = idx & 127;
        T[k][j] = (SN[k][j] - mr[k]) * rs[k] * g_mlp[j] + b_mlp[j];
    }
    __syncthreads();
    // phase 3: HM = gelu(T @ W1 + b1)   (W1 is [128][256])
    for (int jt = 0; jt < 4; ++jt) {
        int j0 = jt << 6;
#pragma unroll
        for (int i = 0; i < 32; ++i) {
            int idx = t + (i << 8);
            int d = idx >> 6, jj = idx & 63;
            wbuf[d * 66 + jj] = W1[d * 256 + j0 + jj];
        }
        __syncthreads();
        {
            int jj = t & 63, rg = t >> 6;
            float a0 = 0.0f, a1 = 0.0f;
            for (int d = 0; d < 128; ++d) {
                float w = wbuf[d * 66 + jj];
                a0 += T[rg][d] * w;
                a1 += T[rg + 4][d] * w;
            }
            float bb = b1[j0 + jj];
            HM[rg][j0 + jj] = gelu_exact(a0 + bb);
            HM[rg + 4][j0 + jj] = gelu_exact(a1 + bb);
        }
        __syncthreads();
    }
    // phase 4: out = SN + HM @ W2 + b2   (W2 is [256][128])
    {
        const int d = t & 127, kk = t >> 7;  // k = kk, kk+2, kk+4, kk+6
        float bb2 = b2[d];
        float a0 = SN[kk][d] + bb2;
        float a1 = SN[kk + 2][d] + bb2;
        float a2 = SN[kk + 4][d] + bb2;
        float a3 = SN[kk + 6][d] + bb2;
        for (int jt = 0; jt < 4; ++jt) {
            int j0 = jt << 6;
#pragma unroll
            for (int i = 0; i < 32; ++i) {
                int idx = t + (i << 8);
                int jj = idx >> 7, dd = idx & 127;
                wbuf[jj * 129 + dd] = W2[(j0 + jj) * D_ + dd];
            }
            __syncthreads();
            for (int jj = 0; jj < 64; ++jj) {
                float w = wbuf[jj * 129 + d];
                a0 += HM[kk][j0 + jj] * w;
                a1 += HM[kk + 2][j0 + jj] * w;
                a2 += HM[kk + 4][j0 + jj] * w;
                a3 += HM[kk + 6][j0 + jj] * w;
            }
            __syncthreads();
        }
        size_t base = (size_t)b * K_ * D_ + d;
        slots[base + (kk)*D_] = a0;
        slots[base + (kk + 2) * D_] = a1;
        slots[base + (kk + 4) * D_] = a2;
        slots[base + (kk + 6) * D_] = a3;
        if (final_iter) {
            out_slots[base + (kk)*D_] = a0;
            out_slots[base + (kk + 2) * D_] = a1;
            out_slots[base + (kk + 4) * D_] = a2;
            out_slots[base + (kk + 6) * D_] = a3;
        }
    }
}

// ---------------------------------------------------------------------------
extern "C" void kernel_launch(void* const* d_in, const int* in_sizes, int n_in,
                              void* d_out, int out_size, void* d_ws, size_t ws_size,
                              hipStream_t stream) {
    const float* x       = (const float*)d_in[0];
    const float* noise   = (const float*)d_in[1];
    const float* slot_mu = (const float*)d_in[2];
    const float* slot_ls = (const float*)d_in[3];
    const float* Wp      = (const float*)d_in[4];
    const float* bp      = (const float*)d_in[5];
    const float* g_in    = (const float*)d_in[6];
    const float* b_in    = (const float*)d_in[7];
    const float* Wq      = (const float*)d_in[8];
    const float* bq      = (const float*)d_in[9];
    const float* Wk      = (const float*)d_in[10];
    const float* bk      = (const float*)d_in[11];
    const float* Wv      = (const float*)d_in[12];
    const float* bv      = (const float*)d_in[13];
    const float* W_ih    = (const float*)d_in[14];
    const float* W_hh    = (const float*)d_in[15];
    const float* b_ih    = (const float*)d_in[16];
    const float* b_hh    = (const float*)d_in[17];
    const float* W1      = (const float*)d_in[18];
    const float* b1      = (const float*)d_in[19];
    const float* W2      = (const float*)d_in[20];
    const float* b2      = (const float*)d_in[21];
    const float* g_slots = (const float*)d_in[22];
    const float* b_slots = (const float*)d_in[23];
    const float* g_mlp   = (const float*)d_in[24];
    const float* b_mlp   = (const float*)d_in[25];

    float* out_slots = (float*)d_out;            // [64,8,128]
    float* out_attn  = (float*)d_out + 65536;    // [64,8,1024]

    // fp32 workspace layout (floats); total ~26M floats = 103.5 MB
    float* wsf    = (float*)d_ws;
    float* inputs = wsf;                   // 65536*128
    float* kbuf   = wsf + 8388608;
    float* vbuf   = wsf + 16777216;
    float* slots  = wsf + 25165824;        // 512*128
    float* qbuf   = slots + 65536;
    float* attn   = qbuf + 65536;          // 64*8*1024
    float* upd    = attn + 524288;

    proj_ln_kernel<<<dim3(1024), dim3(256), 0, stream>>>(x, Wp, bp, g_in, b_in, inputs);
    kv_kernel<<<dim3(1024, 2), dim3(256), 0, stream>>>(inputs, Wk, bk, Wv, bv, kbuf, vbuf);
    slots_init_kernel<<<dim3(256), dim3(256), 0, stream>>>(noise, slot_mu, slot_ls, slots);

    for (int it = 0; it < 3; ++it) {
        int last = (it == 2) ? 1 : 0;
        q_kernel<<<dim3(64), dim3(256), 0, stream>>>(slots, g_slots, b_slots, Wq, bq, qbuf);
        attn_kernel<<<dim3(16, 64), dim3(256), 0, stream>>>(kbuf, qbuf, attn, out_attn, last);
        updates_kernel<<<dim3(64), dim3(256), 0, stream>>>(attn, vbuf, upd);
        gru_mlp_kernel<<<dim3(64), dim3(256), 0, stream>>>(
            upd, slots, W_ih, W_hh, b_ih, b_hh, W1, b1, W2, b2, g_mlp, b_mlp,
            out_slots, last);
    }
}

// Round 4
// 495.498 us; speedup vs baseline: 2.4072x; 2.4072x over previous
//
#include <hip/hip_runtime.h>
#include <hip/hip_bf16.h>
#include <math.h>

#define B_ 64
#define C_ 512
#define N_ 1024
#define D_ 128
#define K_ 8

typedef __attribute__((ext_vector_type(8))) short bf16x8;  // 8 bf16 = 4 VGPRs
typedef __attribute__((ext_vector_type(4))) float f32x4;

__device__ __forceinline__ unsigned short f2bs(float f) {
    union { __hip_bfloat16 h; unsigned short s; } u;
    u.h = __float2bfloat16(f);
    return u.s;
}
__device__ __forceinline__ float bs2f(unsigned short s) {
    union { unsigned int u; float f; } v;
    v.u = ((unsigned int)s) << 16;
    return v.f;
}
__device__ __forceinline__ float sigmoidf_(float x) { return 1.0f / (1.0f + expf(-x)); }
__device__ __forceinline__ float gelu_exact(float x) {
    return 0.5f * x * (1.0f + erff(x * 0.7071067811865476f));
}

// ---------------------------------------------------------------------------
// K1: inputs = LN(x_flat @ Wp + bp)*g+b via MFMA bf16. Block: 64 rows x 128 cols.
// 4 waves in 2x2 grid; wave = 32 rows x 64 cols = 2x4 tiles of 16x16.
// LDS rows padded to 40 shorts (80B = 20 banks -> 2-way conflicts = free).
// Output bf16.
// ---------------------------------------------------------------------------
__global__ __launch_bounds__(256) void proj_ln_mfma(
    const float* __restrict__ x, const float* __restrict__ Wp,
    const float* __restrict__ bp, const float* __restrict__ g_in,
    const float* __restrict__ b_in, unsigned short* __restrict__ outb)
{
    __shared__ unsigned short Al[64 * 40];
    __shared__ unsigned short Bl[128 * 40];
    __shared__ float red[64][2][2];
    const int t = threadIdx.x;
    const int b = blockIdx.x >> 4;
    const int n0 = (blockIdx.x & 15) << 6;
    const int w = t >> 6, lane = t & 63;
    const int quad = lane >> 4, m = lane & 15;
    const int rowoff = (w >> 1) << 5;   // 0 / 32
    const int coloff = (w & 1) << 6;    // 0 / 64

    f32x4 acc[2][4];
#pragma unroll
    for (int r = 0; r < 2; ++r)
#pragma unroll
        for (int c = 0; c < 4; ++c) acc[r][c] = (f32x4){0.f, 0.f, 0.f, 0.f};

    const float* xb = x + (size_t)b * (C_ * N_);
    for (int c0 = 0; c0 < C_; c0 += 32) {
#pragma unroll
        for (int i = 0; i < 8; ++i) {
            int idx = t + (i << 8);
            int cc = idx >> 6, nn = idx & 63;
            Al[nn * 40 + cc] = f2bs(xb[(size_t)(c0 + cc) * N_ + n0 + nn]);
        }
#pragma unroll
        for (int i = 0; i < 16; ++i) {
            int idx = t + (i << 8);
            int cc = idx >> 7, d = idx & 127;
            Bl[d * 40 + cc] = f2bs(Wp[(size_t)(c0 + cc) * D_ + d]);
        }
        __syncthreads();
        bf16x8 af[2], bfr[4];
#pragma unroll
        for (int r = 0; r < 2; ++r)
            af[r] = *(const bf16x8*)&Al[(rowoff + 16 * r + m) * 40 + quad * 8];
#pragma unroll
        for (int c = 0; c < 4; ++c)
            bfr[c] = *(const bf16x8*)&Bl[(coloff + 16 * c + m) * 40 + quad * 8];
#pragma unroll
        for (int r = 0; r < 2; ++r)
#pragma unroll
            for (int c = 0; c < 4; ++c)
                acc[r][c] = __builtin_amdgcn_mfma_f32_16x16x32_bf16(af[r], bfr[c], acc[r][c], 0, 0, 0);
        __syncthreads();
    }
    float gv[4], bv[4], bpv[4];
#pragma unroll
    for (int c = 0; c < 4; ++c) {
        int col = coloff + 16 * c + m;
        bpv[c] = bp[col]; gv[c] = g_in[col]; bv[c] = b_in[col];
    }
#pragma unroll
    for (int r = 0; r < 2; ++r)
#pragma unroll
        for (int c = 0; c < 4; ++c)
#pragma unroll
            for (int g = 0; g < 4; ++g) acc[r][c][g] += bpv[c];

    // per-row partial stats over this wave's 64 cols (quad holds 4 rows)
#pragma unroll
    for (int r = 0; r < 2; ++r) {
#pragma unroll
        for (int g = 0; g < 4; ++g) {
            float s = 0.f, s2 = 0.f;
#pragma unroll
            for (int c = 0; c < 4; ++c) { float v = acc[r][c][g]; s += v; s2 += v * v; }
#pragma unroll
            for (int off = 1; off < 16; off <<= 1) {
                s += __shfl_xor(s, off, 64);
                s2 += __shfl_xor(s2, off, 64);
            }
            if (m == 0) {
                int row = rowoff + 16 * r + quad * 4 + g;
                red[row][w & 1][0] = s;
                red[row][w & 1][1] = s2;
            }
        }
    }
    __syncthreads();
#pragma unroll
    for (int r = 0; r < 2; ++r) {
#pragma unroll
        for (int g = 0; g < 4; ++g) {
            int row = rowoff + 16 * r + quad * 4 + g;
            float s = red[row][0][0] + red[row][1][0];
            float s2 = red[row][0][1] + red[row][1][1];
            float mean = s * (1.f / 128.f);
            float var = s2 * (1.f / 128.f) - mean * mean;
            float rs = rsqrtf(var + 1e-5f);
            size_t base = ((size_t)b * N_ + n0 + row) * D_;
#pragma unroll
            for (int c = 0; c < 4; ++c) {
                int col = coloff + 16 * c + m;
                float v = (acc[r][c][g] - mean) * rs * gv[c] + bv[c];
                outb[base + col] = f2bs(v);
            }
        }
    }
}

// ---------------------------------------------------------------------------
// K2: k = A@Wk + bk ; v = A@Wv + bv (A bf16). Block 64 rows; waves 0,1 -> k,
// waves 2,3 -> v; wave = 32 rows x 128 cols = 2x8 tiles. bf16 outputs.
// ---------------------------------------------------------------------------
__global__ __launch_bounds__(256) void kv_mfma(
    const unsigned short* __restrict__ A,
    const float* __restrict__ Wk, const float* __restrict__ bk,
    const float* __restrict__ Wv, const float* __restrict__ bv,
    unsigned short* __restrict__ kout, unsigned short* __restrict__ vout)
{
    __shared__ unsigned short Al[64 * 40];
    __shared__ unsigned short Bk[128 * 40];
    __shared__ unsigned short Bv[128 * 40];
    const int t = threadIdx.x;
    const int row0 = blockIdx.x << 6;
    const int w = t >> 6, lane = t & 63;
    const int quad = lane >> 4, m = lane & 15;
    const int is_v = w >> 1;
    const int rowoff = (w & 1) << 5;

    f32x4 acc[2][8];
#pragma unroll
    for (int r = 0; r < 2; ++r)
#pragma unroll
        for (int c = 0; c < 8; ++c) acc[r][c] = (f32x4){0.f, 0.f, 0.f, 0.f};

    for (int c0 = 0; c0 < D_; c0 += 32) {
#pragma unroll
        for (int i = 0; i < 2; ++i) {
            int idx = t + (i << 8);
            int rr = idx >> 3, cc4 = (idx & 7) << 2;
            *(ushort4*)&Al[rr * 40 + cc4] =
                *(const ushort4*)&A[(size_t)(row0 + rr) * D_ + c0 + cc4];
        }
#pragma unroll
        for (int i = 0; i < 16; ++i) {
            int idx = t + (i << 8);
            int cc = idx >> 7, d = idx & 127;
            Bk[d * 40 + cc] = f2bs(Wk[(size_t)(c0 + cc) * D_ + d]);
            Bv[d * 40 + cc] = f2bs(Wv[(size_t)(c0 + cc) * D_ + d]);
        }
        __syncthreads();
        const unsigned short* Bsrc = is_v ? Bv : Bk;
        bf16x8 af[2], bfr[8];
#pragma unroll
        for (int r = 0; r < 2; ++r)
            af[r] = *(const bf16x8*)&Al[(rowoff + 16 * r + m) * 40 + quad * 8];
#pragma unroll
        for (int c = 0; c < 8; ++c)
            bfr[c] = *(const bf16x8*)&Bsrc[(16 * c + m) * 40 + quad * 8];
#pragma unroll
        for (int r = 0; r < 2; ++r)
#pragma unroll
            for (int c = 0; c < 8; ++c)
                acc[r][c] = __builtin_amdgcn_mfma_f32_16x16x32_bf16(af[r], bfr[c], acc[r][c], 0, 0, 0);
        __syncthreads();
    }
    const float* bias = is_v ? bv : bk;
    unsigned short* dst = is_v ? vout : kout;
    float bval[8];
#pragma unroll
    for (int c = 0; c < 8; ++c) bval[c] = bias[16 * c + m];
#pragma unroll
    for (int r = 0; r < 2; ++r) {
#pragma unroll
        for (int g = 0; g < 4; ++g) {
            int row = rowoff + 16 * r + quad * 4 + g;
            size_t base = (size_t)(row0 + row) * D_;
#pragma unroll
            for (int c = 0; c < 8; ++c)
                dst[base + 16 * c + m] = f2bs(acc[r][c][g] + bval[c]);
        }
    }
}

// ---------------------------------------------------------------------------
// K3: slots init (fp32)
// ---------------------------------------------------------------------------
__global__ __launch_bounds__(256) void slots_init_kernel(
    const float* __restrict__ noise, const float* __restrict__ mu,
    const float* __restrict__ lsig, float* __restrict__ slots)
{
    int idx = blockIdx.x * 256 + threadIdx.x;
    int kd = idx & (K_ * D_ - 1);
    slots[idx] = mu[kd] + expf(lsig[kd]) * noise[idx];
}

// ---------------------------------------------------------------------------
// K4: per slot-row (512 blocks, 128 thr): q = LN(slots)*g+b @ Wq + bq.
// Also zeroes upd row and S[row] for this iteration's atomics.
// ---------------------------------------------------------------------------
__global__ __launch_bounds__(128) void q_ln_kernel(
    const float* __restrict__ slots, const float* __restrict__ g_slots,
    const float* __restrict__ b_slots, const float* __restrict__ Wq,
    const float* __restrict__ bq, float* __restrict__ qbuf,
    float* __restrict__ upd, float* __restrict__ S)
{
    __shared__ float sl[128], sl2[128];
    __shared__ float mrs[2];
    const int t = threadIdx.x;
    const int row = blockIdx.x;
    sl[t] = slots[(size_t)row * D_ + t];
    upd[(size_t)row * D_ + t] = 0.0f;
    if (t == 0) S[row] = 0.0f;
    __syncthreads();
    if (t < 64) {
        float v0 = sl[t], v1 = sl[t + 64];
        float s = v0 + v1, s2 = v0 * v0 + v1 * v1;
        for (int off = 32; off > 0; off >>= 1) {
            s += __shfl_down(s, off, 64);
            s2 += __shfl_down(s2, off, 64);
        }
        if (t == 0) {
            float mean = s * (1.f / 128.f);
            float var = s2 * (1.f / 128.f) - mean * mean;
            mrs[0] = mean; mrs[1] = rsqrtf(var + 1e-5f);
        }
    }
    __syncthreads();
    sl2[t] = (sl[t] - mrs[0]) * mrs[1] * g_slots[t] + b_slots[t];
    __syncthreads();
    float a = bq[t];
    for (int c = 0; c < 128; ++c) a = fmaf(sl2[c], Wq[(size_t)c * D_ + t], a);
    qbuf[(size_t)row * D_ + t] = a;
}

// ---------------------------------------------------------------------------
// K5a: logits -> softmax over K=8 -> attn; accumulates S[b,k] += sum_n attn.
// grid (16, 64). k is bf16.
// ---------------------------------------------------------------------------
__global__ __launch_bounds__(256) void attn_kernel(
    const unsigned short* __restrict__ kb, const float* __restrict__ qbuf,
    float* __restrict__ attn, float* __restrict__ S,
    float* __restrict__ attn_out, int write_attn)
{
    __shared__ float qs[8][128];
    __shared__ float kt[64][129];
    __shared__ float lg[8][66];
    const int t = threadIdx.x;
    const int n0 = blockIdx.x << 6;
    const int b = blockIdx.y;
    const float SCALE = 0.08838834764831845f;

#pragma unroll
    for (int i = 0; i < 4; ++i) {
        int idx = t + (i << 8);
        int k = idx >> 7, d = idx & 127;
        qs[k][d] = qbuf[((size_t)b * K_ + k) * D_ + d];
    }
#pragma unroll
    for (int i = 0; i < 8; ++i) {
        int idx = t + (i << 8);
        int rr = idx >> 5, d4 = (idx & 31) << 2;
        ushort4 kv4 = *(const ushort4*)&kb[((size_t)b * N_ + n0 + rr) * D_ + d4];
        kt[rr][d4] = bs2f(kv4.x); kt[rr][d4 + 1] = bs2f(kv4.y);
        kt[rr][d4 + 2] = bs2f(kv4.z); kt[rr][d4 + 3] = bs2f(kv4.w);
    }
    __syncthreads();
    {
        int nn = t & 63, kg = t >> 6;
        float a0 = 0.f, a1 = 0.f;
        for (int d = 0; d < 128; ++d) {
            float kv = kt[nn][d];
            a0 = fmaf(qs[kg][d], kv, a0);
            a1 = fmaf(qs[kg + 4][d], kv, a1);
        }
        lg[kg][nn] = a0 * SCALE;
        lg[kg + 4][nn] = a1 * SCALE;
    }
    __syncthreads();
    if (t < 64) {
        float mx = lg[0][t];
#pragma unroll
        for (int k = 1; k < 8; ++k) mx = fmaxf(mx, lg[k][t]);
        float e[8]; float s = 0.f;
#pragma unroll
        for (int k = 0; k < 8; ++k) { e[k] = expf(lg[k][t] - mx); s += e[k]; }
        float inv = 1.0f / s;
#pragma unroll
        for (int k = 0; k < 8; ++k) lg[k][t] = e[k] * inv;
        // partial sums over this block's 64 n per k -> S atomics
#pragma unroll
        for (int k = 0; k < 8; ++k) {
            float pv = e[k] * inv;
            for (int off = 32; off > 0; off >>= 1) pv += __shfl_down(pv, off, 64);
            if (t == 0) atomicAdd(&S[b * K_ + k], pv);
        }
    }
    __syncthreads();
    {
        int nn = t & 63, kg = t >> 6;
        float p0 = lg[kg][nn], p1 = lg[kg + 4][nn];
        size_t i0 = ((size_t)b * K_ + kg) * N_ + n0 + nn;
        size_t i1 = ((size_t)b * K_ + kg + 4) * N_ + n0 + nn;
        attn[i0] = p0;
        attn[i1] = p1;
        if (write_attn) { attn_out[i0] = p0; attn_out[i1] = p1; }
    }
}

// ---------------------------------------------------------------------------
// K5b: partial updates: upd[b,k,:] += sum_{n in chunk} attn * v.  grid (4,64).
// Normalization by 1/(S+eps) happens in gru kernel.
// ---------------------------------------------------------------------------
__global__ __launch_bounds__(256) void updates_kernel(
    const float* __restrict__ attn, const unsigned short* __restrict__ vb,
    float* __restrict__ upd)
{
    __shared__ float vt[64][129];
    __shared__ float at[8][66];
    const int t = threadIdx.x;
    const int b = blockIdx.y;
    const int nbase = blockIdx.x << 8;
    const int d = t & 127, kk = t >> 7;
    float a0 = 0.f, a1 = 0.f, a2 = 0.f, a3 = 0.f;
    for (int st = 0; st < 4; ++st) {
        int n0 = nbase + (st << 6);
#pragma unroll
        for (int i = 0; i < 8; ++i) {
            int idx = t + (i << 8);
            int rr = idx >> 5, d4 = (idx & 31) << 2;
            ushort4 v4 = *(const ushort4*)&vb[((size_t)b * N_ + n0 + rr) * D_ + d4];
            vt[rr][d4] = bs2f(v4.x); vt[rr][d4 + 1] = bs2f(v4.y);
            vt[rr][d4 + 2] = bs2f(v4.z); vt[rr][d4 + 3] = bs2f(v4.w);
        }
#pragma unroll
        for (int i = 0; i < 2; ++i) {
            int idx = t + (i << 8);
            int k = idx >> 6, nn = idx & 63;
            at[k][nn] = attn[((size_t)b * K_ + k) * N_ + n0 + nn];
        }
        __syncthreads();
        for (int nn = 0; nn < 64; ++nn) {
            float vv = vt[nn][d];
            a0 = fmaf(at[kk][nn], vv, a0);
            a1 = fmaf(at[kk + 2][nn], vv, a1);
            a2 = fmaf(at[kk + 4][nn], vv, a2);
            a3 = fmaf(at[kk + 6][nn], vv, a3);
        }
        __syncthreads();
    }
    atomicAdd(&upd[((size_t)b * K_ + kk) * D_ + d], a0);
    atomicAdd(&upd[((size_t)b * K_ + kk + 2) * D_ + d], a1);
    atomicAdd(&upd[((size_t)b * K_ + kk + 4) * D_ + d], a2);
    atomicAdd(&upd[((size_t)b * K_ + kk + 6) * D_ + d], a3);
}

// ---------------------------------------------------------------------------
// K6: per slot-row (512 blocks): GRU + LN + MLP(GELU) + residual.
// ---------------------------------------------------------------------------
__global__ __launch_bounds__(256) void gru_mlp_kernel(
    const float* __restrict__ upd, const float* __restrict__ S,
    float* __restrict__ slots,
    const float* __restrict__ W_ih, const float* __restrict__ W_hh,
    const float* __restrict__ b_ih, const float* __restrict__ b_hh,
    const float* __restrict__ W1, const float* __restrict__ b1,
    const float* __restrict__ W2, const float* __restrict__ b2,
    const float* __restrict__ g_mlp, const float* __restrict__ b_mlp,
    float* __restrict__ out_slots, int final_iter)
{
    __shared__ float u[128], h[128], gx[384], gh[384], sn[128], tt[128], hm[256];
    __shared__ float mrs[2];
    const int t = threadIdx.x;
    const int row = blockIdx.x;
    if (t < 128) {
        float inv = 1.0f / (S[row] + 1e-8f);
        u[t] = upd[(size_t)row * D_ + t] * inv;
        h[t] = slots[(size_t)row * D_ + t];
    }
    __syncthreads();
    {
        const float4* uu = (const float4*)u;
        const float4* hh = (const float4*)h;
        {
            int j = t;
            const float4* wx = (const float4*)(W_ih + (size_t)j * D_);
            const float4* wh = (const float4*)(W_hh + (size_t)j * D_);
            float ax = 0.f, ah = 0.f;
            for (int c = 0; c < 32; ++c) {
                float4 wxv = wx[c], whv = wh[c];
                float4 uv = uu[c], hv = hh[c];
                ax += wxv.x * uv.x + wxv.y * uv.y + wxv.z * uv.z + wxv.w * uv.w;
                ah += whv.x * hv.x + whv.y * hv.y + whv.z * hv.z + whv.w * hv.w;
            }
            gx[j] = ax + b_ih[j];
            gh[j] = ah + b_hh[j];
        }
        if (t < 128) {
            int j = 256 + t;
            const float4* wx = (const float4*)(W_ih + (size_t)j * D_);
            const float4* wh = (const float4*)(W_hh + (size_t)j * D_);
            float ax = 0.f, ah = 0.f;
            for (int c = 0; c < 32; ++c) {
                float4 wxv = wx[c], whv = wh[c];
                float4 uv = uu[c], hv = hh[c];
                ax += wxv.x * uv.x + wxv.y * uv.y + wxv.z * uv.z + wxv.w * uv.w;
                ah += whv.x * hv.x + whv.y * hv.y + whv.z * hv.z + whv.w * hv.w;
            }
            gx[j] = ax + b_ih[j];
            gh[j] = ah + b_hh[j];
        }
    }
    __syncthreads();
    if (t < 128) {
        float r = sigmoidf_(gx[t] + gh[t]);
        float z = sigmoidf_(gx[t + 128] + gh[t + 128]);
        float nv = tanhf(gx[t + 256] + r * gh[t + 256]);
        sn[t] = (1.0f - z) * nv + z * h[t];
    }
    __syncthreads();
    if (t < 64) {
        float v0 = sn[t], v1 = sn[t + 64];
        float s = v0 + v1, s2 = v0 * v0 + v1 * v1;
        for (int off = 32; off > 0; off >>= 1) {
            s += __shfl_down(s, off, 64);
            s2 += __shfl_down(s2, off, 64);
        }
        if (t == 0) {
            float mean = s * (1.f / 128.f);
            float var = s2 * (1.f / 128.f) - mean * mean;
            mrs[0] = mean; mrs[1] = rsqrtf(var + 1e-5f);
        }
    }
    __syncthreads();
    if (t < 128) tt[t] = (sn[t] - mrs[0]) * mrs[1] * g_mlp[t] + b_mlp[t];
    __syncthreads();
    {
        float a = 0.f;
        for (int c = 0; c < 128; ++c) a = fmaf(tt[c], W1[(size_t)c * 256 + t], a);
        hm[t] = gelu_exact(a + b1[t]);
    }
    __syncthreads();
    if (t < 128) {
        float a = sn[t] + b2[t];
        for (int j = 0; j < 256; ++j) a = fmaf(hm[j], W2[(size_t)j * D_ + t], a);
        slots[(size_t)row * D_ + t] = a;
        if (final_iter) out_slots[(size_t)row * D_ + t] = a;
    }
}

// ---------------------------------------------------------------------------
extern "C" void kernel_launch(void* const* d_in, const int* in_sizes, int n_in,
                              void* d_out, int out_size, void* d_ws, size_t ws_size,
                              hipStream_t stream) {
    const float* x       = (const float*)d_in[0];
    const float* noise   = (const float*)d_in[1];
    const float* slot_mu = (const float*)d_in[2];
    const float* slot_ls = (const float*)d_in[3];
    const float* Wp      = (const float*)d_in[4];
    const float* bp      = (const float*)d_in[5];
    const float* g_in    = (const float*)d_in[6];
    const float* b_in    = (const float*)d_in[7];
    const float* Wq      = (const float*)d_in[8];
    const float* bq      = (const float*)d_in[9];
    const float* Wk      = (const float*)d_in[10];
    const float* bk      = (const float*)d_in[11];
    const float* Wv      = (const float*)d_in[12];
    const float* bv      = (const float*)d_in[13];
    const float* W_ih    = (const float*)d_in[14];
    const float* W_hh    = (const float*)d_in[15];
    const float* b_ih    = (const float*)d_in[16];
    const float* b_hh    = (const float*)d_in[17];
    const float* W1      = (const float*)d_in[18];
    const float* b1      = (const float*)d_in[19];
    const float* W2      = (const float*)d_in[20];
    const float* b2      = (const float*)d_in[21];
    const float* g_slots = (const float*)d_in[22];
    const float* b_slots = (const float*)d_in[23];
    const float* g_mlp   = (const float*)d_in[24];
    const float* b_mlp   = (const float*)d_in[25];

    float* out_slots = (float*)d_out;            // [64,8,128] fp32
    float* out_attn  = (float*)d_out + 65536;    // [64,8,1024] fp32

    // workspace layout (float units)
    float* wsf = (float*)d_ws;
    unsigned short* inputsb = (unsigned short*)wsf;               // 65536x128 bf16
    unsigned short* kb = (unsigned short*)(wsf + 4194304);        // 65536x128 bf16
    unsigned short* vb = (unsigned short*)(wsf + 8388608);        // 65536x128 bf16
    float* slots = wsf + 12582912;   // 512*128
    float* qbuf  = wsf + 12648448;   // 512*128
    float* attn  = wsf + 12713984;   // 64*8*1024
    float* upd   = wsf + 13238272;   // 512*128
    float* S     = wsf + 13303808;   // 512

    proj_ln_mfma<<<dim3(1024), dim3(256), 0, stream>>>(x, Wp, bp, g_in, b_in, inputsb);
    kv_mfma<<<dim3(1024), dim3(256), 0, stream>>>(inputsb, Wk, bk, Wv, bv, kb, vb);
    slots_init_kernel<<<dim3(256), dim3(256), 0, stream>>>(noise, slot_mu, slot_ls, slots);

    for (int it = 0; it < 3; ++it) {
        int last = (it == 2) ? 1 : 0;
        q_ln_kernel<<<dim3(512), dim3(128), 0, stream>>>(
            slots, g_slots, b_slots, Wq, bq, qbuf, upd, S);
        attn_kernel<<<dim3(16, 64), dim3(256), 0, stream>>>(
            kb, qbuf, attn, S, out_attn, last);
        updates_kernel<<<dim3(4, 64), dim3(256), 0, stream>>>(attn, vb, upd);
        gru_mlp_kernel<<<dim3(512), dim3(256), 0, stream>>>(
            upd, S, slots, W_ih, W_hh, b_ih, b_hh, W1, b1, W2, b2, g_mlp, b_mlp,
            out_slots, last);
    }
}

// Round 5
// 447.882 us; speedup vs baseline: 2.6631x; 1.1063x over previous
//
#include <hip/hip_runtime.h>
#include <hip/hip_bf16.h>
#include <math.h>

#define B_ 64
#define C_ 512
#define N_ 1024
#define D_ 128
#define K_ 8

typedef __attribute__((ext_vector_type(8))) short bf16x8;  // 8 bf16 = 4 VGPRs
typedef __attribute__((ext_vector_type(4))) float f32x4;
typedef unsigned short ushort_t;

__device__ __forceinline__ unsigned short f2bs(float f) {
    union { __hip_bfloat16 h; unsigned short s; } u;
    u.h = __float2bfloat16(f);
    return u.s;
}
__device__ __forceinline__ float bs2f(unsigned short s) {
    union { unsigned int u; float f; } v;
    v.u = ((unsigned int)s) << 16;
    return v.f;
}
__device__ __forceinline__ float sigmoidf_(float x) { return 1.0f / (1.0f + expf(-x)); }
__device__ __forceinline__ float gelu_exact(float x) {
    return 0.5f * x * (1.0f + erff(x * 0.7071067811865476f));
}

// ---------------------------------------------------------------------------
// K0: weight prep. WpT[d][c]=bf16(Wp[c][d]); WkT/WvT[d][c]=bf16(Wk/Wv[c][d]);
// WTih/WThh[c][j]=W_ih/W_hh[j][c] (fp32). One-time, ~2us.
// ---------------------------------------------------------------------------
__global__ __launch_bounds__(256) void prep_weights(
    const float* __restrict__ Wp, const float* __restrict__ Wk,
    const float* __restrict__ Wv, const float* __restrict__ W_ih,
    const float* __restrict__ W_hh,
    ushort_t* __restrict__ WpT, ushort_t* __restrict__ WkT,
    ushort_t* __restrict__ WvT, float* __restrict__ WTih,
    float* __restrict__ WThh)
{
    int tid = blockIdx.x * 256 + threadIdx.x;   // grid 256*256 = 65536
    {
        int c = tid >> 7, d = tid & 127;        // coalesced read of Wp
        WpT[d * 512 + c] = f2bs(Wp[tid]);
    }
    if (tid < 16384) {
        int c = tid >> 7, d = tid & 127;
        WkT[d * 128 + c] = f2bs(Wk[tid]);
        WvT[d * 128 + c] = f2bs(Wv[tid]);
    }
    if (tid < 49152) {
        int j = tid >> 7, c = tid & 127;        // coalesced read of W_ih
        WTih[c * 384 + j] = W_ih[tid];
        WThh[c * 384 + j] = W_hh[tid];
    }
}

// ---------------------------------------------------------------------------
// K1: inputs = LN(x_flat @ Wp + bp)*g+b via MFMA bf16. Block: 64 rows x 128 cols.
// B staged from pre-converted WpT via ushort8 copies. Output bf16.
// ---------------------------------------------------------------------------
__global__ __launch_bounds__(256) void proj_ln_mfma(
    const float* __restrict__ x, const ushort_t* __restrict__ WpT,
    const float* __restrict__ bp, const float* __restrict__ g_in,
    const float* __restrict__ b_in, ushort_t* __restrict__ outb)
{
    __shared__ ushort_t Al[64 * 40];
    __shared__ ushort_t Bl[128 * 40];
    __shared__ float red[64][2][2];
    const int t = threadIdx.x;
    const int b = blockIdx.x >> 4;
    const int n0 = (blockIdx.x & 15) << 6;
    const int w = t >> 6, lane = t & 63;
    const int quad = lane >> 4, m = lane & 15;
    const int rowoff = (w >> 1) << 5;   // 0 / 32
    const int coloff = (w & 1) << 6;    // 0 / 64

    f32x4 acc[2][4];
#pragma unroll
    for (int r = 0; r < 2; ++r)
#pragma unroll
        for (int c = 0; c < 4; ++c) acc[r][c] = (f32x4){0.f, 0.f, 0.f, 0.f};

    const float* xb = x + (size_t)b * (C_ * N_);
    for (int c0 = 0; c0 < C_; c0 += 32) {
#pragma unroll
        for (int i = 0; i < 8; ++i) {
            int idx = t + (i << 8);
            int cc = idx >> 6, nn = idx & 63;
            Al[nn * 40 + cc] = f2bs(xb[(size_t)(c0 + cc) * N_ + n0 + nn]);
        }
#pragma unroll
        for (int i = 0; i < 2; ++i) {
            int idx = t + (i << 8);           // 0..511
            int d = idx >> 2, seg = idx & 3;  // 128 rows x 4 segs of 8
            *(bf16x8*)&Bl[d * 40 + seg * 8] =
                *(const bf16x8*)&WpT[d * 512 + c0 + seg * 8];
        }
        __syncthreads();
        bf16x8 af[2], bfr[4];
#pragma unroll
        for (int r = 0; r < 2; ++r)
            af[r] = *(const bf16x8*)&Al[(rowoff + 16 * r + m) * 40 + quad * 8];
#pragma unroll
        for (int c = 0; c < 4; ++c)
            bfr[c] = *(const bf16x8*)&Bl[(coloff + 16 * c + m) * 40 + quad * 8];
#pragma unroll
        for (int r = 0; r < 2; ++r)
#pragma unroll
            for (int c = 0; c < 4; ++c)
                acc[r][c] = __builtin_amdgcn_mfma_f32_16x16x32_bf16(af[r], bfr[c], acc[r][c], 0, 0, 0);
        __syncthreads();
    }
    float gv[4], bv[4], bpv[4];
#pragma unroll
    for (int c = 0; c < 4; ++c) {
        int col = coloff + 16 * c + m;
        bpv[c] = bp[col]; gv[c] = g_in[col]; bv[c] = b_in[col];
    }
#pragma unroll
    for (int r = 0; r < 2; ++r)
#pragma unroll
        for (int c = 0; c < 4; ++c)
#pragma unroll
            for (int g = 0; g < 4; ++g) acc[r][c][g] += bpv[c];

#pragma unroll
    for (int r = 0; r < 2; ++r) {
#pragma unroll
        for (int g = 0; g < 4; ++g) {
            float s = 0.f, s2 = 0.f;
#pragma unroll
            for (int c = 0; c < 4; ++c) { float v = acc[r][c][g]; s += v; s2 += v * v; }
#pragma unroll
            for (int off = 1; off < 16; off <<= 1) {
                s += __shfl_xor(s, off, 64);
                s2 += __shfl_xor(s2, off, 64);
            }
            if (m == 0) {
                int row = rowoff + 16 * r + quad * 4 + g;
                red[row][w & 1][0] = s;
                red[row][w & 1][1] = s2;
            }
        }
    }
    __syncthreads();
#pragma unroll
    for (int r = 0; r < 2; ++r) {
#pragma unroll
        for (int g = 0; g < 4; ++g) {
            int row = rowoff + 16 * r + quad * 4 + g;
            float s = red[row][0][0] + red[row][1][0];
            float s2 = red[row][0][1] + red[row][1][1];
            float mean = s * (1.f / 128.f);
            float var = s2 * (1.f / 128.f) - mean * mean;
            float rs = rsqrtf(var + 1e-5f);
            size_t base = ((size_t)b * N_ + n0 + row) * D_;
#pragma unroll
            for (int c = 0; c < 4; ++c) {
                int col = coloff + 16 * c + m;
                float v = (acc[r][c][g] - mean) * rs * gv[c] + bv[c];
                outb[base + col] = f2bs(v);
            }
        }
    }
}

// ---------------------------------------------------------------------------
// K2: k/v = A@Wk/Wv + bias (A bf16, W pre-converted bf16). waves 0,1->k, 2,3->v.
// ---------------------------------------------------------------------------
__global__ __launch_bounds__(256) void kv_mfma(
    const ushort_t* __restrict__ A,
    const ushort_t* __restrict__ WkT, const float* __restrict__ bk,
    const ushort_t* __restrict__ WvT, const float* __restrict__ bv,
    ushort_t* __restrict__ kout, ushort_t* __restrict__ vout)
{
    __shared__ ushort_t Al[64 * 40];
    __shared__ ushort_t Bk[128 * 40];
    __shared__ ushort_t Bv[128 * 40];
    const int t = threadIdx.x;
    const int row0 = blockIdx.x << 6;
    const int w = t >> 6, lane = t & 63;
    const int quad = lane >> 4, m = lane & 15;
    const int is_v = w >> 1;
    const int rowoff = (w & 1) << 5;

    f32x4 acc[2][8];
#pragma unroll
    for (int r = 0; r < 2; ++r)
#pragma unroll
        for (int c = 0; c < 8; ++c) acc[r][c] = (f32x4){0.f, 0.f, 0.f, 0.f};

    for (int c0 = 0; c0 < D_; c0 += 32) {
#pragma unroll
        for (int i = 0; i < 2; ++i) {
            int idx = t + (i << 8);
            int rr = idx >> 3, cc4 = (idx & 7) << 2;
            *(ushort4*)&Al[rr * 40 + cc4] =
                *(const ushort4*)&A[(size_t)(row0 + rr) * D_ + c0 + cc4];
        }
#pragma unroll
        for (int i = 0; i < 2; ++i) {
            int idx = t + (i << 8);
            int d = idx >> 2, seg = idx & 3;
            *(bf16x8*)&Bk[d * 40 + seg * 8] =
                *(const bf16x8*)&WkT[d * 128 + c0 + seg * 8];
            *(bf16x8*)&Bv[d * 40 + seg * 8] =
                *(const bf16x8*)&WvT[d * 128 + c0 + seg * 8];
        }
        __syncthreads();
        const ushort_t* Bsrc = is_v ? Bv : Bk;
        bf16x8 af[2], bfr[8];
#pragma unroll
        for (int r = 0; r < 2; ++r)
            af[r] = *(const bf16x8*)&Al[(rowoff + 16 * r + m) * 40 + quad * 8];
#pragma unroll
        for (int c = 0; c < 8; ++c)
            bfr[c] = *(const bf16x8*)&Bsrc[(16 * c + m) * 40 + quad * 8];
#pragma unroll
        for (int r = 0; r < 2; ++r)
#pragma unroll
            for (int c = 0; c < 8; ++c)
                acc[r][c] = __builtin_amdgcn_mfma_f32_16x16x32_bf16(af[r], bfr[c], acc[r][c], 0, 0, 0);
        __syncthreads();
    }
    const float* bias = is_v ? bv : bk;
    ushort_t* dst = is_v ? vout : kout;
    float bval[8];
#pragma unroll
    for (int c = 0; c < 8; ++c) bval[c] = bias[16 * c + m];
#pragma unroll
    for (int r = 0; r < 2; ++r) {
#pragma unroll
        for (int g = 0; g < 4; ++g) {
            int row = rowoff + 16 * r + quad * 4 + g;
            size_t base = (size_t)(row0 + row) * D_;
#pragma unroll
            for (int c = 0; c < 8; ++c)
                dst[base + 16 * c + m] = f2bs(acc[r][c][g] + bval[c]);
        }
    }
}

// ---------------------------------------------------------------------------
// K3: slots init (fp32)
// ---------------------------------------------------------------------------
__global__ __launch_bounds__(256) void slots_init_kernel(
    const float* __restrict__ noise, const float* __restrict__ mu,
    const float* __restrict__ lsig, float* __restrict__ slots)
{
    int idx = blockIdx.x * 256 + threadIdx.x;
    int kd = idx & (K_ * D_ - 1);
    slots[idx] = mu[kd] + expf(lsig[kd]) * noise[idx];
}

// ---------------------------------------------------------------------------
// K4: per slot-row (512 blocks, 128 thr): q = LN(slots)*g+b @ Wq + bq.
// Also zeroes upd row and S[row] for this iteration's atomics.
// ---------------------------------------------------------------------------
__global__ __launch_bounds__(128) void q_ln_kernel(
    const float* __restrict__ slots, const float* __restrict__ g_slots,
    const float* __restrict__ b_slots, const float* __restrict__ Wq,
    const float* __restrict__ bq, float* __restrict__ qbuf,
    float* __restrict__ upd, float* __restrict__ S)
{
    __shared__ float sl[128], sl2[128];
    __shared__ float mrs[2];
    const int t = threadIdx.x;
    const int row = blockIdx.x;
    sl[t] = slots[(size_t)row * D_ + t];
    upd[(size_t)row * D_ + t] = 0.0f;
    if (t == 0) S[row] = 0.0f;
    __syncthreads();
    if (t < 64) {
        float v0 = sl[t], v1 = sl[t + 64];
        float s = v0 + v1, s2 = v0 * v0 + v1 * v1;
        for (int off = 32; off > 0; off >>= 1) {
            s += __shfl_down(s, off, 64);
            s2 += __shfl_down(s2, off, 64);
        }
        if (t == 0) {
            float mean = s * (1.f / 128.f);
            float var = s2 * (1.f / 128.f) - mean * mean;
            mrs[0] = mean; mrs[1] = rsqrtf(var + 1e-5f);
        }
    }
    __syncthreads();
    sl2[t] = (sl[t] - mrs[0]) * mrs[1] * g_slots[t] + b_slots[t];
    __syncthreads();
    float a = bq[t];
    for (int c = 0; c < 128; ++c) a = fmaf(sl2[c], Wq[(size_t)c * D_ + t], a);
    qbuf[(size_t)row * D_ + t] = a;
}

// ---------------------------------------------------------------------------
// K5a: logits -> softmax over K=8 -> attn; accumulates S[b,k] += sum_n attn.
// ---------------------------------------------------------------------------
__global__ __launch_bounds__(256) void attn_kernel(
    const ushort_t* __restrict__ kb, const float* __restrict__ qbuf,
    float* __restrict__ attn, float* __restrict__ S,
    float* __restrict__ attn_out, int write_attn)
{
    __shared__ float qs[8][128];
    __shared__ float kt[64][129];
    __shared__ float lg[8][66];
    const int t = threadIdx.x;
    const int n0 = blockIdx.x << 6;
    const int b = blockIdx.y;
    const float SCALE = 0.08838834764831845f;

#pragma unroll
    for (int i = 0; i < 4; ++i) {
        int idx = t + (i << 8);
        int k = idx >> 7, d = idx & 127;
        qs[k][d] = qbuf[((size_t)b * K_ + k) * D_ + d];
    }
#pragma unroll
    for (int i = 0; i < 8; ++i) {
        int idx = t + (i << 8);
        int rr = idx >> 5, d4 = (idx & 31) << 2;
        ushort4 kv4 = *(const ushort4*)&kb[((size_t)b * N_ + n0 + rr) * D_ + d4];
        kt[rr][d4] = bs2f(kv4.x); kt[rr][d4 + 1] = bs2f(kv4.y);
        kt[rr][d4 + 2] = bs2f(kv4.z); kt[rr][d4 + 3] = bs2f(kv4.w);
    }
    __syncthreads();
    {
        int nn = t & 63, kg = t >> 6;
        float a0 = 0.f, a1 = 0.f;
        for (int d = 0; d < 128; ++d) {
            float kv = kt[nn][d];
            a0 = fmaf(qs[kg][d], kv, a0);
            a1 = fmaf(qs[kg + 4][d], kv, a1);
        }
        lg[kg][nn] = a0 * SCALE;
        lg[kg + 4][nn] = a1 * SCALE;
    }
    __syncthreads();
    if (t < 64) {
        float mx = lg[0][t];
#pragma unroll
        for (int k = 1; k < 8; ++k) mx = fmaxf(mx, lg[k][t]);
        float e[8]; float s = 0.f;
#pragma unroll
        for (int k = 0; k < 8; ++k) { e[k] = expf(lg[k][t] - mx); s += e[k]; }
        float inv = 1.0f / s;
#pragma unroll
        for (int k = 0; k < 8; ++k) lg[k][t] = e[k] * inv;
#pragma unroll
        for (int k = 0; k < 8; ++k) {
            float pv = e[k] * inv;
            for (int off = 32; off > 0; off >>= 1) pv += __shfl_down(pv, off, 64);
            if (t == 0) atomicAdd(&S[b * K_ + k], pv);
        }
    }
    __syncthreads();
    {
        int nn = t & 63, kg = t >> 6;
        float p0 = lg[kg][nn], p1 = lg[kg + 4][nn];
        size_t i0 = ((size_t)b * K_ + kg) * N_ + n0 + nn;
        size_t i1 = ((size_t)b * K_ + kg + 4) * N_ + n0 + nn;
        attn[i0] = p0;
        attn[i1] = p1;
        if (write_attn) { attn_out[i0] = p0; attn_out[i1] = p1; }
    }
}

// ---------------------------------------------------------------------------
// K5b: partial updates: upd[b,k,:] += sum_{n in chunk} attn * v.  grid (4,64).
// ---------------------------------------------------------------------------
__global__ __launch_bounds__(256) void updates_kernel(
    const float* __restrict__ attn, const ushort_t* __restrict__ vb,
    float* __restrict__ upd)
{
    __shared__ float vt[64][129];
    __shared__ float at[8][66];
    const int t = threadIdx.x;
    const int b = blockIdx.y;
    const int nbase = blockIdx.x << 8;
    const int d = t & 127, kk = t >> 7;
    float a0 = 0.f, a1 = 0.f, a2 = 0.f, a3 = 0.f;
    for (int st = 0; st < 4; ++st) {
        int n0 = nbase + (st << 6);
#pragma unroll
        for (int i = 0; i < 8; ++i) {
            int idx = t + (i << 8);
            int rr = idx >> 5, d4 = (idx & 31) << 2;
            ushort4 v4 = *(const ushort4*)&vb[((size_t)b * N_ + n0 + rr) * D_ + d4];
            vt[rr][d4] = bs2f(v4.x); vt[rr][d4 + 1] = bs2f(v4.y);
            vt[rr][d4 + 2] = bs2f(v4.z); vt[rr][d4 + 3] = bs2f(v4.w);
        }
#pragma unroll
        for (int i = 0; i < 2; ++i) {
            int idx = t + (i << 8);
            int k = idx >> 6, nn = idx & 63;
            at[k][nn] = attn[((size_t)b * K_ + k) * N_ + n0 + nn];
        }
        __syncthreads();
        for (int nn = 0; nn < 64; ++nn) {
            float vv = vt[nn][d];
            a0 = fmaf(at[kk][nn], vv, a0);
            a1 = fmaf(at[kk + 2][nn], vv, a1);
            a2 = fmaf(at[kk + 4][nn], vv, a2);
            a3 = fmaf(at[kk + 6][nn], vv, a3);
        }
        __syncthreads();
    }
    atomicAdd(&upd[((size_t)b * K_ + kk) * D_ + d], a0);
    atomicAdd(&upd[((size_t)b * K_ + kk + 2) * D_ + d], a1);
    atomicAdd(&upd[((size_t)b * K_ + kk + 4) * D_ + d], a2);
    atomicAdd(&upd[((size_t)b * K_ + kk + 6) * D_ + d], a3);
}

// ---------------------------------------------------------------------------
// K6: per slot-row (512 blocks): GRU + LN + MLP(GELU) + residual.
// W_ih/W_hh accessed via pre-transposed WTih/WThh (coalesced).
// ---------------------------------------------------------------------------
__global__ __launch_bounds__(256) void gru_mlp_kernel(
    const float* __restrict__ upd, const float* __restrict__ S,
    float* __restrict__ slots,
    const float* __restrict__ WTih, const float* __restrict__ WThh,
    const float* __restrict__ b_ih, const float* __restrict__ b_hh,
    const float* __restrict__ W1, const float* __restrict__ b1,
    const float* __restrict__ W2, const float* __restrict__ b2,
    const float* __restrict__ g_mlp, const float* __restrict__ b_mlp,
    float* __restrict__ out_slots, int final_iter)
{
    __shared__ float u[128], h[128], gx[384], gh[384], sn[128], tt[128], hm[256];
    __shared__ float mrs[2];
    const int t = threadIdx.x;
    const int row = blockIdx.x;
    if (t < 128) {
        float inv = 1.0f / (S[row] + 1e-8f);
        u[t] = upd[(size_t)row * D_ + t] * inv;
        h[t] = slots[(size_t)row * D_ + t];
    }
    __syncthreads();
    {
        int j = t;
        float ax = 0.f, ah = 0.f;
        for (int c = 0; c < 128; ++c) {
            float uc = u[c], hc = h[c];
            ax = fmaf(uc, WTih[(size_t)c * 384 + j], ax);
            ah = fmaf(hc, WThh[(size_t)c * 384 + j], ah);
        }
        gx[j] = ax + b_ih[j];
        gh[j] = ah + b_hh[j];
    }
    if (t < 128) {
        int j = 256 + t;
        float ax = 0.f, ah = 0.f;
        for (int c = 0; c < 128; ++c) {
            float uc = u[c], hc = h[c];
            ax = fmaf(uc, WTih[(size_t)c * 384 + j], ax);
            ah = fmaf(hc, WThh[(size_t)c * 384 + j], ah);
        }
        gx[j] = ax + b_ih[j];
        gh[j] = ah + b_hh[j];
    }
    __syncthreads();
    if (t < 128) {
        float r = sigmoidf_(gx[t] + gh[t]);
        float z = sigmoidf_(gx[t + 128] + gh[t + 128]);
        float nv = tanhf(gx[t + 256] + r * gh[t + 256]);
        sn[t] = (1.0f - z) * nv + z * h[t];
    }
    __syncthreads();
    if (t < 64) {
        float v0 = sn[t], v1 = sn[t + 64];
        float s = v0 + v1, s2 = v0 * v0 + v1 * v1;
        for (int off = 32; off > 0; off >>= 1) {
            s += __shfl_down(s, off, 64);
            s2 += __shfl_down(s2, off, 64);
        }
        if (t == 0) {
            float mean = s * (1.f / 128.f);
            float var = s2 * (1.f / 128.f) - mean * mean;
            mrs[0] = mean; mrs[1] = rsqrtf(var + 1e-5f);
        }
    }
    __syncthreads();
    if (t < 128) tt[t] = (sn[t] - mrs[0]) * mrs[1] * g_mlp[t] + b_mlp[t];
    __syncthreads();
    {
        float a = 0.f;
        for (int c = 0; c < 128; ++c) a = fmaf(tt[c], W1[(size_t)c * 256 + t], a);
        hm[t] = gelu_exact(a + b1[t]);
    }
    __syncthreads();
    if (t < 128) {
        float a = sn[t] + b2[t];
        for (int j = 0; j < 256; ++j) a = fmaf(hm[j], W2[(size_t)j * D_ + t], a);
        slots[(size_t)row * D_ + t] = a;
        if (final_iter) out_slots[(size_t)row * D_ + t] = a;
    }
}

// ---------------------------------------------------------------------------
extern "C" void kernel_launch(void* const* d_in, const int* in_sizes, int n_in,
                              void* d_out, int out_size, void* d_ws, size_t ws_size,
                              hipStream_t stream) {
    const float* x       = (const float*)d_in[0];
    const float* noise   = (const float*)d_in[1];
    const float* slot_mu = (const float*)d_in[2];
    const float* slot_ls = (const float*)d_in[3];
    const float* Wp      = (const float*)d_in[4];
    const float* bp      = (const float*)d_in[5];
    const float* g_in    = (const float*)d_in[6];
    const float* b_in    = (const float*)d_in[7];
    const float* Wq      = (const float*)d_in[8];
    const float* bq      = (const float*)d_in[9];
    const float* Wk      = (const float*)d_in[10];
    const float* bk      = (const float*)d_in[11];
    const float* Wv      = (const float*)d_in[12];
    const float* bv      = (const float*)d_in[13];
    const float* W_ih    = (const float*)d_in[14];
    const float* W_hh    = (const float*)d_in[15];
    const float* b_ih    = (const float*)d_in[16];
    const float* b_hh    = (const float*)d_in[17];
    const float* W1      = (const float*)d_in[18];
    const float* b1      = (const float*)d_in[19];
    const float* W2      = (const float*)d_in[20];
    const float* b2      = (const float*)d_in[21];
    const float* g_slots = (const float*)d_in[22];
    const float* b_slots = (const float*)d_in[23];
    const float* g_mlp   = (const float*)d_in[24];
    const float* b_mlp   = (const float*)d_in[25];

    float* out_slots = (float*)d_out;            // [64,8,128] fp32
    float* out_attn  = (float*)d_out + 65536;    // [64,8,1024] fp32

    // workspace layout (float units)
    float* wsf = (float*)d_ws;
    ushort_t* inputsb = (ushort_t*)wsf;                    // 65536x128 bf16
    ushort_t* kb = (ushort_t*)(wsf + 4194304);             // 65536x128 bf16
    ushort_t* vb = (ushort_t*)(wsf + 8388608);             // 65536x128 bf16
    float* slots = wsf + 12582912;   // 512*128
    float* qbuf  = wsf + 12648448;   // 512*128
    float* attn  = wsf + 12713984;   // 64*8*1024
    float* upd   = wsf + 13238272;   // 512*128
    float* S     = wsf + 13303808;   // 512
    ushort_t* WpT = (ushort_t*)(wsf + 13304320);  // 128x512 bf16
    ushort_t* WkT = (ushort_t*)(wsf + 13337088);  // 128x128 bf16
    ushort_t* WvT = (ushort_t*)(wsf + 13345280);  // 128x128 bf16
    float* WTih = wsf + 13353472;    // 128x384 fp32
    float* WThh = wsf + 13402624;    // 128x384 fp32

    prep_weights<<<dim3(256), dim3(256), 0, stream>>>(
        Wp, Wk, Wv, W_ih, W_hh, WpT, WkT, WvT, WTih, WThh);
    proj_ln_mfma<<<dim3(1024), dim3(256), 0, stream>>>(x, WpT, bp, g_in, b_in, inputsb);
    kv_mfma<<<dim3(1024), dim3(256), 0, stream>>>(inputsb, WkT, bk, WvT, bv, kb, vb);
    slots_init_kernel<<<dim3(256), dim3(256), 0, stream>>>(noise, slot_mu, slot_ls, slots);

    for (int it = 0; it < 3; ++it) {
        int last = (it == 2) ? 1 : 0;
        q_ln_kernel<<<dim3(512), dim3(128), 0, stream>>>(
            slots, g_slots, b_slots, Wq, bq, qbuf, upd, S);
        attn_kernel<<<dim3(16, 64), dim3(256), 0, stream>>>(
            kb, qbuf, attn, S, out_attn, last);
        updates_kernel<<<dim3(4, 64), dim3(256), 0, stream>>>(attn, vb, upd);
        gru_mlp_kernel<<<dim3(512), dim3(256), 0, stream>>>(
            upd, S, slots, WTih, WThh, b_ih, b_hh, W1, b1, W2, b2, g_mlp, b_mlp,
            out_slots, last);
    }
}